// Round 1
// baseline (465.437 us; speedup 1.0000x reference)
//
#include <hip/hip_runtime.h>
#include <hip/hip_bf16.h>
#include <stdint.h>

// StaticGraphLSTMCell: B=512, N=21, I=256, H=1024, NT=5
// out = [hy (B*N*H) | cy (B*N*H) | gx_out (N*N)] fp32
//
// ws layout (bytes):
//   Wc   bf16 [5][4096][1280]   @ 0          (52,428,800)
//   Xc   bf16 [21][512][1280]   @ 52,428,800 (27,525,120)
//   gates bf16 [512][21][4096]  @ 79,953,920 (88,080,384)
//   gx   f32  [21][21]          @ 168,034,304 (1,764)
// total ~168 MB

typedef __bf16 bf16_t;
typedef __bf16 bf16x8 __attribute__((ext_vector_type(8)));
typedef float f32x4 __attribute__((ext_vector_type(4)));

#define NB 512
#define NN 21
#define NI 256
#define NH 1024
#define KDIM 1280
#define ODIM 4096
#define BNH (512ull * 21 * 1024)

__device__ inline void gld16(const void* g, const void* l) {
  __builtin_amdgcn_global_load_lds(
      (const __attribute__((address_space(1))) unsigned int*)g,
      (__attribute__((address_space(3))) unsigned int*)l, 16, 0, 0);
}

__device__ inline float sigmoid_fast(float x) {
  return 1.0f / (1.0f + __expf(-x));
}
__device__ inline float tanh_fast(float x) {
  float ax = fabsf(x);
  float e = __expf(2.0f * ax);          // inf-safe: 2/(inf+1)=0 -> 1
  float t = 1.0f - 2.0f / (e + 1.0f);
  return copysignf(t, x);
}

// ---- gx: L1 row-normalize G; gxw = normalize(G); gxout = normalize(gxw) ----
__global__ void gx_kernel(const float* __restrict__ G, float* __restrict__ gxw,
                          float* __restrict__ gxout) {
  int m = threadIdx.x;
  if (m < NN) {
    float s = 0.f;
    for (int j = 0; j < NN; j++) s += fabsf(G[m * NN + j]);
    s = fmaxf(s, 1e-12f);
    float row[NN];
    float s2 = 0.f;
    for (int j = 0; j < NN; j++) {
      row[j] = G[m * NN + j] / s;
      s2 += fabsf(row[j]);
    }
    s2 = fmaxf(s2, 1e-12f);
    for (int j = 0; j < NN; j++) {
      gxw[m * NN + j] = row[j];
      gxout[m * NN + j] = row[j] / s2;
    }
  }
}

// ---- pack weights: Wc[tau*4096+o][k] = k<256 ? wih[tau*4096+o][k] : whh[...][k-256]
__global__ __launch_bounds__(256) void pack_w(const float* __restrict__ wih,
                                              const float* __restrict__ whh,
                                              bf16_t* __restrict__ Wc) {
  int idx = blockIdx.x * 256 + threadIdx.x;  // 5*4096*1280 = 26,214,400
  if (idx >= 5 * ODIM * KDIM) return;
  int k = idx % KDIM;
  int row = idx / KDIM;  // tau*4096 + o
  float v = (k < NI) ? wih[(size_t)row * NI + k] : whh[(size_t)row * NH + (k - NI)];
  Wc[idx] = (bf16_t)v;
}

// ---- pack activations: Xc[n][b][k] = k<256 ? input[b][n][k] : hx[b][n][k-256]
__global__ __launch_bounds__(256) void pack_x(const float* __restrict__ input,
                                              const float* __restrict__ hx,
                                              bf16_t* __restrict__ Xc) {
  int idx = blockIdx.x * 256 + threadIdx.x;  // 21*512*1280 = 13,762,560
  if (idx >= NN * NB * KDIM) return;
  int k = idx % KDIM;
  int rest = idx / KDIM;  // n*512 + b
  int n = rest / NB;
  int b = rest % NB;
  float v = (k < NI) ? input[((size_t)b * NN + n) * NI + k]
                     : hx[((size_t)b * NN + n) * NH + (k - NI)];
  Xc[idx] = (bf16_t)v;
}

// ---- GEMM: per node n (blockIdx.z): gates[b][n][o] = Xc[n][b][:] . Wc[tau][o][:] + bias
// m97 structure: BM=BN=128, BK=32, 256 threads (4 waves in 2x2), 16x16x32 bf16 MFMA
__global__ __launch_bounds__(256) void gemm_bt(const bf16_t* __restrict__ Xc,
                                               const bf16_t* __restrict__ Wc,
                                               const float* __restrict__ bhh,
                                               const int* __restrict__ node_types,
                                               bf16_t* __restrict__ gates) {
  __shared__ bf16_t As[128 * 32];
  __shared__ bf16_t Bs[128 * 32];

  const int n = blockIdx.z;
  const int tau = node_types[n];
  const bf16_t* A = Xc + (size_t)n * NB * KDIM;
  const bf16_t* B = Wc + (size_t)tau * ODIM * KDIM;

  const int tid = threadIdx.x;
  const int m0 = blockIdx.y * 128;
  const int n0 = blockIdx.x * 128;

  const int lane = tid & 63;
  const int wv = tid >> 6;
  const int wm = (wv >> 1) * 64;
  const int wn = (wv & 1) * 64;
  const int r = lane & 15;
  const int quad = lane >> 4;

  f32x4 acc[4][4];
#pragma unroll
  for (int i = 0; i < 4; i++)
#pragma unroll
    for (int j = 0; j < 4; j++) acc[i][j] = {0.f, 0.f, 0.f, 0.f};

  const int srow = tid >> 2;           // 0..63 (row within 64-row half)
  const int schunk = (tid & 3) * 8;    // k element offset: 0,8,16,24

  for (int k0 = 0; k0 < KDIM; k0 += 32) {
    gld16(A + (size_t)(m0 + srow) * KDIM + k0 + schunk, (char*)As + tid * 16);
    gld16(A + (size_t)(m0 + 64 + srow) * KDIM + k0 + schunk, (char*)As + 4096 + tid * 16);
    gld16(B + (size_t)(n0 + srow) * KDIM + k0 + schunk, (char*)Bs + tid * 16);
    gld16(B + (size_t)(n0 + 64 + srow) * KDIM + k0 + schunk, (char*)Bs + 4096 + tid * 16);
    __syncthreads();

    bf16x8 af[4], bfr[4];
#pragma unroll
    for (int i = 0; i < 4; i++)
      af[i] = *(const bf16x8*)&As[(wm + i * 16 + r) * 32 + quad * 8];
#pragma unroll
    for (int j = 0; j < 4; j++)
      bfr[j] = *(const bf16x8*)&Bs[(wn + j * 16 + r) * 32 + quad * 8];
#pragma unroll
    for (int i = 0; i < 4; i++)
#pragma unroll
      for (int j = 0; j < 4; j++)
        acc[i][j] = __builtin_amdgcn_mfma_f32_16x16x32_bf16(af[i], bfr[j], acc[i][j], 0, 0, 0);
    __syncthreads();
  }

  // epilogue: C/D layout col=lane&15, row=quad*4+reg (verified m89/m91)
  float bv[4];
#pragma unroll
  for (int j = 0; j < 4; j++) bv[j] = bhh[tau * ODIM + n0 + wn + j * 16 + r];
#pragma unroll
  for (int i = 0; i < 4; i++) {
    int brow = m0 + wm + i * 16 + quad * 4;
#pragma unroll
    for (int j = 0; j < 4; j++) {
      int o = n0 + wn + j * 16 + r;
#pragma unroll
      for (int reg = 0; reg < 4; reg++) {
        int b = brow + reg;
        gates[((size_t)b * NN + n) * ODIM + o] = (bf16_t)(acc[i][j][reg] + bv[j]);
      }
    }
  }
}

// ---- mix + LSTM pointwise: one thread per (b,h)
__global__ __launch_bounds__(256) void mix_kernel(const bf16_t* __restrict__ gates,
                                                  const float* __restrict__ gx,
                                                  const float* __restrict__ cx,
                                                  const int* __restrict__ t_ptr,
                                                  float* __restrict__ out) {
  __shared__ float gxs[NN * NN];
  int tid = threadIdx.x;
  for (int i = tid; i < NN * NN; i += 256) gxs[i] = gx[i];
  __syncthreads();

  int idx = blockIdx.x * 256 + tid;  // 512*1024
  int b = idx >> 10;
  int h = idx & 1023;

  float vals[NN * 4];
#pragma unroll
  for (int n = 0; n < NN; n++)
#pragma unroll
    for (int g = 0; g < 4; g++)
      vals[n * 4 + g] = (float)gates[((size_t)b * NN + n) * ODIM + g * NH + h];

  int t = t_ptr[0];
  float phase = floorf(((float)h / 1023.0f) * 8.0f + 1.0f);  // 1..9
  float fm = fmodf((float)(t + 1), phase);
  bool cmask = fm < 0.01f;

  for (int m = 0; m < NN; m++) {
    float s0 = 0.f, s1 = 0.f, s2 = 0.f, s3 = 0.f;
#pragma unroll
    for (int n = 0; n < NN; n++) {
      float w = gxs[m * NN + n];
      s0 += w * vals[n * 4 + 0];
      s1 += w * vals[n * 4 + 1];
      s2 += w * vals[n * 4 + 2];
      s3 += w * vals[n * 4 + 3];
    }
    float ig = sigmoid_fast(s0);
    float fg = sigmoid_fast(s1);
    float cg = tanh_fast(s2);
    float og = sigmoid_fast(s3);
    size_t off = ((size_t)b * NN + m) * NH + h;
    float cxv = cx[off];
    float cy = cmask ? (fg * cxv + ig * cg) : cxv;
    float hy = og * tanh_fast(cy);
    out[off] = hy;
    out[BNH + off] = cy;
  }
}

extern "C" void kernel_launch(void* const* d_in, const int* in_sizes, int n_in,
                              void* d_out, int out_size, void* d_ws, size_t ws_size,
                              hipStream_t stream) {
  const float* input = (const float*)d_in[0];
  const float* hx = (const float*)d_in[1];
  const float* cx = (const float*)d_in[2];
  const float* G = (const float*)d_in[3];
  const float* wih = (const float*)d_in[4];
  const float* whh = (const float*)d_in[5];
  const float* bhh = (const float*)d_in[6];
  const int* node_types = (const int*)d_in[7];
  const int* t = (const int*)d_in[8];
  float* out = (float*)d_out;

  char* ws = (char*)d_ws;
  bf16_t* Wc = (bf16_t*)ws;                        // 52,428,800 B
  bf16_t* Xc = (bf16_t*)(ws + 52428800);           // 27,525,120 B
  bf16_t* gates = (bf16_t*)(ws + 79953920);        // 88,080,384 B
  float* gxw = (float*)(ws + 168034304);           // 1,764 B

  gx_kernel<<<1, 64, 0, stream>>>(G, gxw, out + 2 * BNH);
  pack_w<<<(5 * ODIM * KDIM) / 256, 256, 0, stream>>>(wih, whh, Wc);
  pack_x<<<(NN * NB * KDIM) / 256, 256, 0, stream>>>(input, hx, Xc);
  dim3 gg(ODIM / 128, NB / 128, NN);
  gemm_bt<<<gg, 256, 0, stream>>>(Xc, Wc, bhh, node_types, gates);
  mix_kernel<<<(NB * NH) / 256, 256, 0, stream>>>(gates, gxw, cx, t, out);
}

// Round 2
// 458.797 us; speedup vs baseline: 1.0145x; 1.0145x over previous
//
#include <hip/hip_runtime.h>
#include <hip/hip_bf16.h>
#include <stdint.h>

// StaticGraphLSTMCell: B=512, N=21, I=256, H=1024, NT=5
// out = [hy (B*N*H) | cy (B*N*H) | gx_out (N*N)] fp32
//
// ws layout (bytes):
//   Wc   bf16 [5][4096][1280]   @ 0          (52,428,800)
//   Xc   bf16 [21][512][1280]   @ 52,428,800 (27,525,120)
//   gates bf16 [512][21][4096]  @ 79,953,920 (88,080,384)  (mixed in-place)
//   gx   f32  [21][21]          @ 168,034,304 (1,764)

typedef __bf16 bf16_t;
typedef __bf16 bf16x8 __attribute__((ext_vector_type(8)));
typedef float f32x4 __attribute__((ext_vector_type(4)));

#define NB 512
#define NN 21
#define NI 256
#define NH 1024
#define KDIM 1280
#define ODIM 4096
#define BNH (512ull * 21 * 1024)

__device__ inline void gld16(const void* g, const void* l) {
  __builtin_amdgcn_global_load_lds(
      (const __attribute__((address_space(1))) unsigned int*)g,
      (__attribute__((address_space(3))) unsigned int*)l, 16, 0, 0);
}

__device__ inline float sigmoid_fast(float x) {
  return 1.0f / (1.0f + __expf(-x));
}
__device__ inline float tanh_fast(float x) {
  float ax = fabsf(x);
  float e = __expf(2.0f * ax);  // inf-safe: 2/(inf+1)=0 -> 1
  float t = 1.0f - 2.0f / (e + 1.0f);
  return copysignf(t, x);
}

// ---- gx: L1 row-normalize G; gxw = normalize(G); gxout = normalize(gxw) ----
__global__ void gx_kernel(const float* __restrict__ G, float* __restrict__ gxw,
                          float* __restrict__ gxout) {
  int m = threadIdx.x;
  if (m < NN) {
    float s = 0.f;
    for (int j = 0; j < NN; j++) s += fabsf(G[m * NN + j]);
    s = fmaxf(s, 1e-12f);
    float row[NN];
    float s2 = 0.f;
    for (int j = 0; j < NN; j++) {
      row[j] = G[m * NN + j] / s;
      s2 += fabsf(row[j]);
    }
    s2 = fmaxf(s2, 1e-12f);
    for (int j = 0; j < NN; j++) {
      gxw[m * NN + j] = row[j];
      gxout[m * NN + j] = row[j] / s2;
    }
  }
}

// ---- pack weights (8 elems/thread): Wc[row][k] = k<256 ? wih : whh
__global__ __launch_bounds__(256) void pack_w(const float* __restrict__ wih,
                                              const float* __restrict__ whh,
                                              bf16_t* __restrict__ Wc) {
  int c = blockIdx.x * 256 + threadIdx.x;  // chunk of 8; total 3,276,800
  int k8 = c % (KDIM / 8);
  int row = c / (KDIM / 8);  // tau*4096 + o
  int k = k8 * 8;
  const float* src = (k < NI) ? (wih + (size_t)row * NI + k)
                              : (whh + (size_t)row * NH + (k - NI));
  float4 a = *(const float4*)src;
  float4 b = *(const float4*)(src + 4);
  bf16x8 o;
  o[0] = (bf16_t)a.x; o[1] = (bf16_t)a.y; o[2] = (bf16_t)a.z; o[3] = (bf16_t)a.w;
  o[4] = (bf16_t)b.x; o[5] = (bf16_t)b.y; o[6] = (bf16_t)b.z; o[7] = (bf16_t)b.w;
  *(bf16x8*)&Wc[(size_t)c * 8] = o;
}

// ---- pack activations (8 elems/thread): Xc[n][b][k] = k<256 ? input : hx
__global__ __launch_bounds__(256) void pack_x(const float* __restrict__ input,
                                              const float* __restrict__ hx,
                                              bf16_t* __restrict__ Xc) {
  int c = blockIdx.x * 256 + threadIdx.x;  // chunk of 8; total 1,720,320
  int k8 = c % (KDIM / 8);
  int rest = c / (KDIM / 8);  // n*512 + b
  int n = rest / NB;
  int b = rest % NB;
  int k = k8 * 8;
  const float* src = (k < NI) ? (input + ((size_t)b * NN + n) * NI + k)
                              : (hx + ((size_t)b * NN + n) * NH + (k - NI));
  float4 a = *(const float4*)src;
  float4 d = *(const float4*)(src + 4);
  bf16x8 o;
  o[0] = (bf16_t)a.x; o[1] = (bf16_t)a.y; o[2] = (bf16_t)a.z; o[3] = (bf16_t)a.w;
  o[4] = (bf16_t)d.x; o[5] = (bf16_t)d.y; o[6] = (bf16_t)d.z; o[7] = (bf16_t)d.w;
  *(bf16x8*)&Xc[(size_t)c * 8] = o;
}

// ---- GEMM: per node n (blockIdx.z): gates[b][n][o] = Xc[n][b][:] . Wc[tau][o][:] + bias
__global__ __launch_bounds__(256) void gemm_bt(const bf16_t* __restrict__ Xc,
                                               const bf16_t* __restrict__ Wc,
                                               const float* __restrict__ bhh,
                                               const int* __restrict__ node_types,
                                               bf16_t* __restrict__ gates) {
  __shared__ bf16_t As[128 * 32];
  __shared__ bf16_t Bs[128 * 32];

  const int n = blockIdx.z;
  const int tau = node_types[n];
  const bf16_t* A = Xc + (size_t)n * NB * KDIM;
  const bf16_t* B = Wc + (size_t)tau * ODIM * KDIM;

  const int tid = threadIdx.x;
  const int m0 = blockIdx.y * 128;
  const int n0 = blockIdx.x * 128;

  const int lane = tid & 63;
  const int wv = tid >> 6;
  const int wm = (wv >> 1) * 64;
  const int wn = (wv & 1) * 64;
  const int r = lane & 15;
  const int quad = lane >> 4;

  f32x4 acc[4][4];
#pragma unroll
  for (int i = 0; i < 4; i++)
#pragma unroll
    for (int j = 0; j < 4; j++) acc[i][j] = {0.f, 0.f, 0.f, 0.f};

  const int srow = tid >> 2;
  const int schunk = (tid & 3) * 8;

  for (int k0 = 0; k0 < KDIM; k0 += 32) {
    gld16(A + (size_t)(m0 + srow) * KDIM + k0 + schunk, (char*)As + tid * 16);
    gld16(A + (size_t)(m0 + 64 + srow) * KDIM + k0 + schunk, (char*)As + 4096 + tid * 16);
    gld16(B + (size_t)(n0 + srow) * KDIM + k0 + schunk, (char*)Bs + tid * 16);
    gld16(B + (size_t)(n0 + 64 + srow) * KDIM + k0 + schunk, (char*)Bs + 4096 + tid * 16);
    __syncthreads();

    bf16x8 af[4], bfr[4];
#pragma unroll
    for (int i = 0; i < 4; i++)
      af[i] = *(const bf16x8*)&As[(wm + i * 16 + r) * 32 + quad * 8];
#pragma unroll
    for (int j = 0; j < 4; j++)
      bfr[j] = *(const bf16x8*)&Bs[(wn + j * 16 + r) * 32 + quad * 8];
#pragma unroll
    for (int i = 0; i < 4; i++)
#pragma unroll
      for (int j = 0; j < 4; j++)
        acc[i][j] = __builtin_amdgcn_mfma_f32_16x16x32_bf16(af[i], bfr[j], acc[i][j], 0, 0, 0);
    __syncthreads();
  }

  float bv[4];
#pragma unroll
  for (int j = 0; j < 4; j++) bv[j] = bhh[tau * ODIM + n0 + wn + j * 16 + r];
#pragma unroll
  for (int i = 0; i < 4; i++) {
    int brow = m0 + wm + i * 16 + quad * 4;
#pragma unroll
    for (int j = 0; j < 4; j++) {
      int o = n0 + wn + j * 16 + r;
#pragma unroll
      for (int reg = 0; reg < 4; reg++) {
        int b = brow + reg;
        gates[((size_t)b * NN + n) * ODIM + o] = (bf16_t)(acc[i][j][reg] + bv[j]);
      }
    }
  }
}

// ---- mix over nodes (in-place): gates[b][m][o-range] = sum_n gx[m][n]*gates[b][n][o-range]
// block = (o-chunk of 512, b). Stage 21x512 bf16 (42KB) in LDS; read-all-then-write => in-place safe.
__global__ __launch_bounds__(256) void mix_lin(bf16_t* __restrict__ gates,
                                               const float* __restrict__ gx) {
  __shared__ float gxs[NN * NN];
  __shared__ bf16_t gs[NN * 512];
  const int tid = threadIdx.x;
  for (int i = tid; i < NN * NN; i += 256) gxs[i] = gx[i];
  const int b = blockIdx.y;
  const int o0 = blockIdx.x * 512;
  const size_t base = (size_t)b * NN * ODIM + o0;

  for (int i = tid; i < NN * 64; i += 256) {
    int n = i / 64, c = i % 64;
    *(bf16x8*)&gs[n * 512 + c * 8] = *(const bf16x8*)&gates[base + (size_t)n * ODIM + c * 8];
  }
  __syncthreads();

  for (int i = tid; i < NN * 64; i += 256) {
    int m = i / 64, c = i % 64;
    float acc[8];
#pragma unroll
    for (int j = 0; j < 8; j++) acc[j] = 0.f;
    for (int n = 0; n < NN; n++) {
      float w = gxs[m * NN + n];
      bf16x8 v = *(const bf16x8*)&gs[n * 512 + c * 8];
#pragma unroll
      for (int j = 0; j < 8; j++) acc[j] += w * (float)v[j];
    }
    bf16x8 o;
#pragma unroll
    for (int j = 0; j < 8; j++) o[j] = (bf16_t)acc[j];
    *(bf16x8*)&gates[base + (size_t)m * ODIM + c * 8] = o;
  }
}

// ---- pointwise LSTM: 8 h per thread, fully vectorized
__global__ __launch_bounds__(256) void lstm_pw(const bf16_t* __restrict__ gates,
                                               const float* __restrict__ cx,
                                               const int* __restrict__ t_ptr,
                                               float* __restrict__ out) {
  int idx = blockIdx.x * 256 + threadIdx.x;  // total 512*21*128 = 5376*256
  int h8 = idx % 128;
  int bm = idx / 128;  // b*21 + m
  int h = h8 * 8;
  int t = t_ptr[0];
  size_t gbase = (size_t)bm * ODIM;
  bf16x8 vi = *(const bf16x8*)&gates[gbase + 0 * NH + h];
  bf16x8 vf = *(const bf16x8*)&gates[gbase + 1 * NH + h];
  bf16x8 vc = *(const bf16x8*)&gates[gbase + 2 * NH + h];
  bf16x8 vo = *(const bf16x8*)&gates[gbase + 3 * NH + h];
  size_t off = (size_t)bm * NH + h;
  float4 c0 = *(const float4*)&cx[off];
  float4 c1 = *(const float4*)&cx[off + 4];
  float cxv[8] = {c0.x, c0.y, c0.z, c0.w, c1.x, c1.y, c1.z, c1.w};
  float hy[8], cy[8];
  float tf = (float)(t + 1);
#pragma unroll
  for (int j = 0; j < 8; j++) {
    float phase = floorf(((float)(h + j)) / 1023.0f * 8.0f + 1.0f);  // 1..9
    bool cmask = fmodf(tf, phase) < 0.01f;
    float ig = sigmoid_fast((float)vi[j]);
    float fg = sigmoid_fast((float)vf[j]);
    float cg = tanh_fast((float)vc[j]);
    float og = sigmoid_fast((float)vo[j]);
    float c = cmask ? (fg * cxv[j] + ig * cg) : cxv[j];
    cy[j] = c;
    hy[j] = og * tanh_fast(c);
  }
  *(float4*)&out[off] = make_float4(hy[0], hy[1], hy[2], hy[3]);
  *(float4*)&out[off + 4] = make_float4(hy[4], hy[5], hy[6], hy[7]);
  *(float4*)&out[BNH + off] = make_float4(cy[0], cy[1], cy[2], cy[3]);
  *(float4*)&out[BNH + off + 4] = make_float4(cy[4], cy[5], cy[6], cy[7]);
}

extern "C" void kernel_launch(void* const* d_in, const int* in_sizes, int n_in,
                              void* d_out, int out_size, void* d_ws, size_t ws_size,
                              hipStream_t stream) {
  const float* input = (const float*)d_in[0];
  const float* hx = (const float*)d_in[1];
  const float* cx = (const float*)d_in[2];
  const float* G = (const float*)d_in[3];
  const float* wih = (const float*)d_in[4];
  const float* whh = (const float*)d_in[5];
  const float* bhh = (const float*)d_in[6];
  const int* node_types = (const int*)d_in[7];
  const int* t = (const int*)d_in[8];
  float* out = (float*)d_out;

  char* ws = (char*)d_ws;
  bf16_t* Wc = (bf16_t*)ws;
  bf16_t* Xc = (bf16_t*)(ws + 52428800);
  bf16_t* gates = (bf16_t*)(ws + 79953920);
  float* gxw = (float*)(ws + 168034304);

  gx_kernel<<<1, 64, 0, stream>>>(G, gxw, out + 2 * BNH);
  pack_w<<<(5 * ODIM * KDIM / 8) / 256, 256, 0, stream>>>(wih, whh, Wc);
  pack_x<<<(NN * NB * KDIM / 8) / 256, 256, 0, stream>>>(input, hx, Xc);
  dim3 gg(ODIM / 128, NB / 128, NN);
  gemm_bt<<<gg, 256, 0, stream>>>(Xc, Wc, bhh, node_types, gates);
  dim3 gm(ODIM / 512, NB);
  mix_lin<<<gm, 256, 0, stream>>>(gates, gxw);
  lstm_pw<<<(NB * NN * (NH / 8)) / 256, 256, 0, stream>>>(gates, cx, t, out);
}